// Round 1
// baseline (932.406 us; speedup 1.0000x reference)
//
#include <hip/hip_runtime.h>
#include <hip/hip_bf16.h>

// TemporalEMA: out = ALPHA * bilinear_warp(prev_hidden, mv) + (1-ALPHA) * current
// Shapes: current/prev_hidden [B=4, C=16, H=1080, W=1920] f32, mv [B, 2, H, W] f32.
// grid_sample semantics: border padding (clamp), align_corners=True.
// Pixel-space collapse: px = clamp(w - mv_x*(W-1)/W, 0, W-1), same for y.

#define ALPHA 0.85f

constexpr int Bc = 4;
constexpr int Cc = 16;
constexpr int Hc = 1080;
constexpr int Wc = 1920;

__global__ __launch_bounds__(256) void TemporalEMA_73194832658797_kernel(
    const float* __restrict__ cur,
    const float* __restrict__ prev,
    const float* __restrict__ mv,
    float* __restrict__ out)
{
    int idx = blockIdx.x * blockDim.x + threadIdx.x;   // over B*H*W
    const int total = Bc * Hc * Wc;
    if (idx >= total) return;

    const int w  = idx % Wc;
    const int hb = idx / Wc;
    const int h  = hb % Hc;
    const int b  = hb / Hc;

    const size_t plane = (size_t)Hc * Wc;
    const size_t pix   = (size_t)h * Wc + w;

    // mv layout [B, 2, H, W]
    const float mvx = mv[((size_t)b * 2 + 0) * plane + pix];
    const float mvy = mv[((size_t)b * 2 + 1) * plane + pix];

    // sample coords in pixel space (border clamp)
    const float sxk = (float)(Wc - 1) / (float)Wc;   // (W-1)/W
    const float syk = (float)(Hc - 1) / (float)Hc;
    float px = fminf(fmaxf((float)w - mvx * sxk, 0.0f), (float)(Wc - 1));
    float py = fminf(fmaxf((float)h - mvy * syk, 0.0f), (float)(Hc - 1));

    const float x0f = floorf(px);
    const float y0f = floorf(py);
    const float wx = px - x0f;
    const float wy = py - y0f;
    const int x0 = (int)x0f;
    const int y0 = (int)y0f;
    const int x1 = min(x0 + 1, Wc - 1);
    const int y1 = min(y0 + 1, Hc - 1);

    const float w00 = (1.0f - wx) * (1.0f - wy);
    const float w01 = wx * (1.0f - wy);
    const float w10 = (1.0f - wx) * wy;
    const float w11 = wx * wy;

    const size_t o00 = (size_t)y0 * Wc + x0;
    const size_t o01 = (size_t)y0 * Wc + x1;
    const size_t o10 = (size_t)y1 * Wc + x0;
    const size_t o11 = (size_t)y1 * Wc + x1;

    const size_t base_b = (size_t)b * Cc * plane;

    #pragma unroll
    for (int c = 0; c < Cc; ++c) {
        const size_t cb = base_b + (size_t)c * plane;
        const float v00 = prev[cb + o00];
        const float v01 = prev[cb + o01];
        const float v10 = prev[cb + o10];
        const float v11 = prev[cb + o11];
        const float warped = v00 * w00 + v01 * w01 + v10 * w10 + v11 * w11;
        const float cu = cur[cb + pix];
        out[cb + pix] = ALPHA * warped + (1.0f - ALPHA) * cu;
    }
}

extern "C" void kernel_launch(void* const* d_in, const int* in_sizes, int n_in,
                              void* d_out, int out_size, void* d_ws, size_t ws_size,
                              hipStream_t stream) {
    const float* cur  = (const float*)d_in[0];
    const float* prev = (const float*)d_in[1];
    const float* mv   = (const float*)d_in[2];
    float* out = (float*)d_out;

    const int total = Bc * Hc * Wc;           // threads: one per (b,h,w)
    const int block = 256;
    const int grid  = (total + block - 1) / block;
    TemporalEMA_73194832658797_kernel<<<grid, block, 0, stream>>>(cur, prev, mv, out);
}

// Round 2
// 704.006 us; speedup vs baseline: 1.3244x; 1.3244x over previous
//
#include <hip/hip_runtime.h>
#include <hip/hip_bf16.h>

// TemporalEMA: out = ALPHA * bilinear_warp(prev_hidden, mv) + (1-ALPHA) * current
// R2: 2D tiles (64w x 4h) + chunked-XCD swizzle for y-halo L2 locality,
//     nontemporal for streamed cur/mv/out, channel-group-4 ILP.

#define ALPHA 0.85f

constexpr int Bc = 4;
constexpr int Cc = 16;
constexpr int Hc = 1080;
constexpr int Wc = 1920;

constexpr int TW = 64;            // tile width  (one wave = one row chunk)
constexpr int TH = 4;             // tile height (4 waves per block)
constexpr int NX = Wc / TW;       // 30
constexpr int NY = Hc / TH;       // 270
constexpr int NBLK = Bc * NY * NX; // 32400
constexpr int NXCD = 8;
constexpr int CHUNK = NBLK / NXCD; // 4050 (NBLK % 8 == 0 -> bijective)

__global__ __launch_bounds__(256) void TemporalEMA_73194832658797_kernel(
    const float* __restrict__ cur,
    const float* __restrict__ prev,
    const float* __restrict__ mv,
    float* __restrict__ out)
{
    // Chunked XCD swizzle: HW round-robins consecutive blockIdx across 8 XCDs;
    // remap so each XCD processes a contiguous slab of (b, ty, tx) work ->
    // y-halo gather lines stay resident in that XCD's 4MB L2.
    const int bid  = blockIdx.x;
    const int work = (bid % NXCD) * CHUNK + bid / NXCD;

    const int tx  = work % NX;
    const int rem = work / NX;
    const int ty  = rem % NY;
    const int b   = rem / NY;

    const int lane_w = threadIdx.x & (TW - 1);
    const int lane_h = threadIdx.x / TW;
    const int w = tx * TW + lane_w;
    const int h = ty * TH + lane_h;

    const size_t plane = (size_t)Hc * Wc;
    const size_t pix   = (size_t)h * Wc + w;

    // mv layout [B, 2, H, W] (streamed once -> nontemporal)
    const float mvx = __builtin_nontemporal_load(&mv[((size_t)b * 2 + 0) * plane + pix]);
    const float mvy = __builtin_nontemporal_load(&mv[((size_t)b * 2 + 1) * plane + pix]);

    // pixel-space sample coords, border clamp (align_corners=True collapse)
    const float sxk = (float)(Wc - 1) / (float)Wc;
    const float syk = (float)(Hc - 1) / (float)Hc;
    float px = fminf(fmaxf((float)w - mvx * sxk, 0.0f), (float)(Wc - 1));
    float py = fminf(fmaxf((float)h - mvy * syk, 0.0f), (float)(Hc - 1));

    const float x0f = floorf(px);
    const float y0f = floorf(py);
    const float wx = px - x0f;
    const float wy = py - y0f;
    const int x0 = (int)x0f;
    const int y0 = (int)y0f;
    const int x1 = min(x0 + 1, Wc - 1);
    const int y1 = min(y0 + 1, Hc - 1);

    const float w00 = (1.0f - wx) * (1.0f - wy);
    const float w01 = wx * (1.0f - wy);
    const float w10 = (1.0f - wx) * wy;
    const float w11 = wx * wy;

    const size_t o00 = (size_t)y0 * Wc + x0;
    const size_t o01 = (size_t)y0 * Wc + x1;
    const size_t o10 = (size_t)y1 * Wc + x0;
    const size_t o11 = (size_t)y1 * Wc + x1;

    const size_t base_b = (size_t)b * Cc * plane;

    #pragma unroll
    for (int cg = 0; cg < Cc; cg += 4) {
        float v00[4], v01[4], v10[4], v11[4], cu[4];
        #pragma unroll
        for (int j = 0; j < 4; ++j) {
            const size_t cb = base_b + (size_t)(cg + j) * plane;
            v00[j] = prev[cb + o00];
            v01[j] = prev[cb + o01];
            v10[j] = prev[cb + o10];
            v11[j] = prev[cb + o11];
            cu[j]  = __builtin_nontemporal_load(&cur[cb + pix]);
        }
        #pragma unroll
        for (int j = 0; j < 4; ++j) {
            const size_t cb = base_b + (size_t)(cg + j) * plane;
            const float warped = v00[j] * w00 + v01[j] * w01 + v10[j] * w10 + v11[j] * w11;
            __builtin_nontemporal_store(ALPHA * warped + (1.0f - ALPHA) * cu[j], &out[cb + pix]);
        }
    }
}

extern "C" void kernel_launch(void* const* d_in, const int* in_sizes, int n_in,
                              void* d_out, int out_size, void* d_ws, size_t ws_size,
                              hipStream_t stream) {
    const float* cur  = (const float*)d_in[0];
    const float* prev = (const float*)d_in[1];
    const float* mv   = (const float*)d_in[2];
    float* out = (float*)d_out;

    TemporalEMA_73194832658797_kernel<<<NBLK, 256, 0, stream>>>(cur, prev, mv, out);
}